// Round 12
// baseline (472.364 us; speedup 1.0000x reference)
//
#include <hip/hip_runtime.h>
#include <hip/hip_bf16.h>

typedef unsigned int u32;
typedef unsigned short u16;
typedef __attribute__((ext_vector_type(8))) short short8;   // 8 bf16 (4 VGPRs)
typedef __attribute__((ext_vector_type(4))) float f32x4;    // MFMA C/D
typedef __attribute__((ext_vector_type(2))) float f32x2;    // v_pk_fma_f32 operand

#define N_PTS 100000
#define NSAMP 16

__device__ __forceinline__ float lo2f(u32 u){ return __uint_as_float(u << 16); }
__device__ __forceinline__ float hi2f(u32 u){ return __uint_as_float(u & 0xffff0000u); }
__device__ __forceinline__ float us2f(u16 u){ return __uint_as_float(((u32)u) << 16); }

// round-to-nearest-even f32 -> bf16 bits (finite values only)
__device__ __forceinline__ u16 f2bf(float f) {
    u32 u = __float_as_uint(f);
    return (u16)((u + 0x7fffu + ((u >> 16) & 1u)) >> 16);
}
__device__ __forceinline__ u32 pack2(float k, float v) {
    return (u32)f2bf(k) | ((u32)f2bf(v) << 16);
}

// wave-local LDS RAW fence. The "memory" clobber ALSO pins global loads
// above it (they cannot sink past) — R4/R11-proven mechanism that keeps
// the whole gather burst issued up-front.
#define WAVE_LDS_FENCE() asm volatile("s_waitcnt lgkmcnt(0)" ::: "memory")

// Runtime input-dtype probe (must be called by ALL threads of the block).
__device__ __forceinline__ bool detect_f32(const u16* __restrict__ xprobe) {
    float f = us2f(xprobe[(threadIdx.x & 63) * 2]);
    int cnt = __syncthreads_count(fabsf(f) > 1024.0f ? 1 : 0);
    return cnt >= 8;
}

// generic raw-weight element load (fp32 or bf16 source)
__device__ __forceinline__ float rawf(const void* s, int i, bool isf32) {
    return isf32 ? ((const float*)s)[i] : us2f(((const u16*)s)[i]);
}

// canonical fp32 weight-block offsets (floats) — written by qkv block 0,
// consumed by attn (stream-ordered).
#define OFF_WP1  0
#define OFF_BP1  12
#define OFF_GP   16
#define OFF_BP   20
#define OFF_WP2  24
#define OFF_BP2  216
#define OFF_G1   280
#define OFF_BB1  344
#define OFF_BA   408
#define OFF_G2   416
#define OFF_BB2  424
#define OFF_BW   432
#define OFF_WAT  448     /* WaT[s][c] : 8 x 64 f32 (transposed Wa) */
#define OFF_WBT  960     /* WbT[t][s] : 8 x 8  f32 (transposed Wb) */
#define CW_PAD   4096    /* pad to 16 KB of floats */

// ---------------------------------------------------------------------------
// K1: MFMA QKV projection + (block 0) attn-weight canonicalization.
// Round-12: TPB 5 -> 10 (amortize per-block B-frag build). Grid 625.
// ---------------------------------------------------------------------------
#define QKV_TPB 10
__global__ __launch_bounds__(256) void qkv_mfma_kernel(
    const u16* __restrict__ xraw,
    const void* s0,  const void* s1,  const void* s2,  const void* s3,
    const void* s4,  const void* s5,  const void* s6,  const void* s7,
    const void* s8,  const void* s9,  const void* s10, const void* s11,
    const void* s12, const void* s13, const void* s14, const void* s15,
    const void* s16, const void* s17, const void* s18, const void* s19,
    float* __restrict__ cw,
    float* __restrict__ Q, u32* __restrict__ KV)
{
    bool isf32 = detect_f32(xraw);
    const int w   = threadIdx.x >> 6;
    const int l   = threadIdx.x & 63;
    const int col = l & 15;
    const int g   = l >> 4;

    // ---- block 0: write attn's canonical weight block ----
    if (blockIdx.x == 0) {
        const void* srcs[12] = {s6,s7,s8,s9,s10,s11,s12,s13,s15,s16,s17,s19};
        const int   sizes[12]= {9,3,3,3,192,64,64,64,8,8,8,8};
        const int   offs[12] = {OFF_WP1,OFF_BP1,OFF_GP,OFF_BP,OFF_WP2,OFF_BP2,
                                OFF_G1,OFF_BB1,OFF_BA,OFF_G2,OFF_BB2,OFF_BW};
        int tid = threadIdx.x;
        for (int a = 0; a < 12; a++)
            for (int k = tid; k < sizes[a]; k += 256)
                cw[offs[a] + k] = rawf(srcs[a], k, isf32);
        // WaT[s][c] = Wa[c][s] ; WbT[t][s] = Wb[s][t]
        for (int t = tid; t < 512 + 64; t += 256) {
            if (t < 512) {
                int s = t >> 6, cc = t & 63;
                cw[OFF_WAT + s * 64 + cc] = rawf(s14, cc * 8 + s, isf32);
            } else {
                int r = t - 512;
                int tt = r >> 3, ss = r & 7;
                cw[OFF_WBT + tt * 8 + ss] = rawf(s18, ss * 8 + tt, isf32);
            }
        }
    }

    // ---- build B fragments (weights) in registers: hi/lo bf16 planes ----
    const void* wsrc[3] = {s0, s2, s4};
    short8 bh[3][2], bl[3][2];
#pragma unroll
    for (int m = 0; m < 3; m++)
#pragma unroll
        for (int kh = 0; kh < 2; kh++)
#pragma unroll
            for (int j = 0; j < 8; j++) {
                float wv_ = rawf(wsrc[m], (kh * 32 + g * 8 + j) * 64 + w * 16 + col, isf32);
                u16 hb = f2bf(wv_);
                bh[m][kh][j] = (short)hb;
                bl[m][kh][j] = (short)f2bf(wv_ - us2f(hb));
            }
    const float bqc = rawf(s1, w * 16 + col, isf32);
    const float bkc = rawf(s3, w * 16 + col, isf32);
    const float bvc = rawf(s5, w * 16 + col, isf32);

#define LOAD_A(IT, AH, AL)                                                        \
    {                                                                             \
        const int M0_ = (blockIdx.x * QKV_TPB + (IT)) * 16;                       \
        if (isf32) {                                                              \
            const float4* xf = (const float4*)xraw;                               \
            _Pragma("unroll")                                                     \
            for (int kh = 0; kh < 2; kh++) {                                      \
                float4 f0 = xf[(size_t)(M0_ + col) * 16 + kh * 8 + g * 2];        \
                float4 f1 = xf[(size_t)(M0_ + col) * 16 + kh * 8 + g * 2 + 1];    \
                float ff[8] = {f0.x, f0.y, f0.z, f0.w, f1.x, f1.y, f1.z, f1.w};   \
                _Pragma("unroll")                                                 \
                for (int j = 0; j < 8; j++) {                                     \
                    u16 hb_ = f2bf(ff[j]);                                        \
                    AH[kh][j] = (short)hb_;                                       \
                    AL[kh][j] = (short)f2bf(ff[j] - us2f(hb_));                   \
                }                                                                 \
            }                                                                     \
        } else {                                                                  \
            const short8* xb = (const short8*)xraw;                               \
            _Pragma("unroll")                                                     \
            for (int kh = 0; kh < 2; kh++)                                        \
                AH[kh] = xb[(size_t)(M0_ + col) * 8 + kh * 4 + g];                \
        }                                                                         \
    }

    short8 ahA[2], alA[2], ahB[2], alB[2];
    LOAD_A(0, ahA, alA);

#pragma unroll
    for (int it = 0; it < QKV_TPB; it++) {
        short8 (&ah)[2] = (it & 1) ? ahB : ahA;
        short8 (&al)[2] = (it & 1) ? alB : alA;
        short8 (&ahN)[2] = (it & 1) ? ahA : ahB;
        short8 (&alN)[2] = (it & 1) ? alA : alB;
        if (it + 1 < QKV_TPB) LOAD_A(it + 1, ahN, alN);

        const int M0 = (blockIdx.x * QKV_TPB + it) * 16;
        f32x4 aQ = {bqc, bqc, bqc, bqc};
        f32x4 aK = {bkc, bkc, bkc, bkc};
        f32x4 aV = {bvc, bvc, bvc, bvc};

#pragma unroll
        for (int kh = 0; kh < 2; kh++) {
            aQ = __builtin_amdgcn_mfma_f32_16x16x32_bf16(ah[kh], bh[0][kh], aQ, 0, 0, 0);
            aK = __builtin_amdgcn_mfma_f32_16x16x32_bf16(ah[kh], bh[1][kh], aK, 0, 0, 0);
            aV = __builtin_amdgcn_mfma_f32_16x16x32_bf16(ah[kh], bh[2][kh], aV, 0, 0, 0);
            aQ = __builtin_amdgcn_mfma_f32_16x16x32_bf16(ah[kh], bl[0][kh], aQ, 0, 0, 0);
            aK = __builtin_amdgcn_mfma_f32_16x16x32_bf16(ah[kh], bl[1][kh], aK, 0, 0, 0);
            aV = __builtin_amdgcn_mfma_f32_16x16x32_bf16(ah[kh], bl[2][kh], aV, 0, 0, 0);
            if (isf32) {
                aQ = __builtin_amdgcn_mfma_f32_16x16x32_bf16(al[kh], bh[0][kh], aQ, 0, 0, 0);
                aK = __builtin_amdgcn_mfma_f32_16x16x32_bf16(al[kh], bh[1][kh], aK, 0, 0, 0);
                aV = __builtin_amdgcn_mfma_f32_16x16x32_bf16(al[kh], bh[2][kh], aV, 0, 0, 0);
            }
        }

#pragma unroll
        for (int r = 0; r < 4; r++) {
            int row = M0 + g * 4 + r;
            Q [(size_t)row * 64 + w * 16 + col] = aQ[r];
            KV[(size_t)row * 64 + w * 16 + col] = pack2(aK[r], aV[r]);
        }
    }
#undef LOAD_A
}

// ---------------------------------------------------------------------------
// K2: fused attention — round 12: FOUR POINTS PER WAVE, phased wvbuf.
// All 64 KV gathers issue in one pinned burst (lgkmcnt fence, R11-proven);
// stage1/stage2 run in two phases over the same 8 wvbuf slices (pts 0,1
// then 2,3) so LDS stays ~55 KB -> 2 blocks/CU = 8 waves/CU x 64
// outstanding gathers = 512/CU (R11: ~336). Math bit-identical to R11.
// Block = 4 waves x 4 pts = 16 points; grid = 6250 exactly.
// ---------------------------------------------------------------------------
__global__ __launch_bounds__(256, 2) void attn_kernel(
    const u16* __restrict__ P, const int* __restrict__ IDX,
    const u16* __restrict__ xprobe, const float* __restrict__ cw,
    const float* __restrict__ Q, const u32* __restrict__ KV,
    void* __restrict__ OUT)
{
    __shared__ __align__(16) float wvbuf[8][NSAMP * 68];   // phased: 2 slices/wave
    __shared__ __align__(16) float tbbuf[16][NSAMP * 8];   // per-point
    __shared__ __align__(16) float w2buf[16][NSAMP * 8];   // per-point
    __shared__ __align__(16) float hbuf[16][NSAMP * 4];    // per-point

    bool isf32 = detect_f32(xprobe);

    const int pt = threadIdx.x >> 6;
    const int c  = threadIdx.x & 63;
    const int ib = blockIdx.x * 16 + pt * 4;   // grid*16 == N_PTS exactly
    const float rs = 1.0f / sqrtf(1.0f + 1e-5f);

    // ================= BURST: 4 IDX + 64 KV gathers + 4 Q + P =============
    int jv[4];
#pragma unroll
    for (int p = 0; p < 4; p++)
        jv[p] = IDX[(size_t)(ib + p) * NSAMP + (c & 15)];

    u32 kvw[4][NSAMP];
    const u32* KVc = KV + c;
#pragma unroll
    for (int p = 0; p < 4; p++)
#pragma unroll
        for (int n = 0; n < NSAMP; n++) {
            int j = __builtin_amdgcn_readlane(jv[p], n);   // SGPR -> SALU addr
            kvw[p][n] = KVc[(size_t)j << 6];
        }

    float qq[4];
#pragma unroll
    for (int p = 0; p < 4; p++)
        qq[p] = Q[(size_t)(ib + p) * 64 + c];

    // ---- distributed h-MLP (4 points): lane (n,d) = (c/3, c%3) ----
    const float* Pf = (const float*)P;
    const int n_p  = c / 3;
    const int d_p  = c - n_p * 3;
    const int np15 = n_p & 15;
    const int lb   = np15 * 3;
    {
        float gd  = cw[OFF_GP + d_p] * rs;
        float w0s = cw[OFF_WP1 + 0 * 3 + d_p] * gd;
        float w1s = cw[OFF_WP1 + 1 * 3 + d_p] * gd;
        float w2s = cw[OFF_WP1 + 2 * 3 + d_p] * gd;
        float bs  = cw[OFF_BP1 + d_p] * gd + cw[OFF_BP + d_p];
#pragma unroll
        for (int p = 0; p < 4; p++) {
            int jp = __shfl(jv[p], np15, 64);
            float pj, pid;
            if (isf32) { pj = Pf[(size_t)jp * 3 + d_p]; pid = Pf[(size_t)(ib + p) * 3 + d_p]; }
            else       { pj = us2f(P[(size_t)jp * 3 + d_p]); pid = us2f(P[(size_t)(ib + p) * 3 + d_p]); }
            float pr = pj - pid;
            float d0 = __shfl(pr, lb + 0, 64);
            float d1 = __shfl(pr, lb + 1, 64);
            float d2 = __shfl(pr, lb + 2, 64);
            float h = fmaxf(fmaf(d2, w2s, fmaf(d1, w1s, fmaf(d0, w0s, bs))), 0.0f);
            if (c < 48) hbuf[pt * 4 + p][np15 * 4 + d_p] = h;
        }
    }
    WAVE_LDS_FENCE();   // hbuf RAW (same wave) + pins ALL 64 gathers above

    // per-lane channel constants (L1-hot)
    const float wp2c0 = cw[OFF_WP2 + 0 * 64 + c];
    const float wp2c1 = cw[OFF_WP2 + 1 * 64 + c];
    const float wp2c2 = cw[OFF_WP2 + 2 * 64 + c];
    const float bp2c  = cw[OFF_BP2 + c];
    const float g1c   = cw[OFF_G1  + c] * rs;
    const float bb1c  = cw[OFF_BB1 + c];
    const int s2s = c & 7, s2n = c >> 3;
    const float4* waT4 = (const float4*)(cw + OFF_WAT + s2s * 64);
    const float ba_s  = cw[OFF_BA + s2s];
    const float g2s   = cw[OFF_G2 + s2s] * rs;
    const float bb2s  = cw[OFF_BB2 + s2s];

    float pv[4][NSAMP];

    // ================= two phases: {stage1, stage2} x (2 points each) ======
#pragma unroll
    for (int ph = 0; ph < 2; ph++) {
        // ---- stage 1: relation input into wvbuf slice pt*2+q ----
#pragma unroll
        for (int q = 0; q < 2; q++) {
            const int p = ph * 2 + q;
#pragma unroll
            for (int n = 0; n < NSAMP; n++) {
                float4 hb = *((const float4*)&hbuf[pt * 4 + p][n * 4]);
                float pe = fmaf(hb.z, wp2c2, fmaf(hb.y, wp2c1, fmaf(hb.x, wp2c0, bp2c)));
                float kk = lo2f(kvw[p][n]);
                float vv = hi2f(kvw[p][n]);
                wvbuf[pt * 2 + q][n * 68 + c] = fmaxf(fmaf(kk - qq[p] + pe, g1c, bb1c), 0.0f);
                pv[p][n] = vv + pe;
            }
        }
        __syncthreads();

        // ---- stage 2 (merged reps, f32x2 packed) -> tbbuf[pt*4+p] ----
#pragma unroll
        for (int q = 0; q < 2; q++) {
            const int p = ph * 2 + q;
            f32x2 a0v = {ba_s, 0.0f};
            f32x2 a1v = a0v;
#pragma unroll
            for (int c4 = 0; c4 < 16; c4++) {
                float4 wa  = waT4[c4];
                float4 w40 = *((const float4*)&wvbuf[pt * 2 + q][s2n * 68 + c4 * 4]);
                float4 w41 = *((const float4*)&wvbuf[pt * 2 + q][(s2n + 8) * 68 + c4 * 4]);
                f32x2 waA = {wa.x, wa.y},  waB = {wa.z, wa.w};
                f32x2 p0A = {w40.x, w40.y}, p0B = {w40.z, w40.w};
                f32x2 p1A = {w41.x, w41.y}, p1B = {w41.z, w41.w};
                a0v += p0A * waA;  a0v += p0B * waB;
                a1v += p1A * waA;  a1v += p1B * waB;
            }
            tbbuf[pt * 4 + p][s2n * 8 + s2s]       = fmaxf(fmaf(a0v.x + a0v.y, g2s, bb2s), 0.0f);
            tbbuf[pt * 4 + p][(s2n + 8) * 8 + s2s] = fmaxf(fmaf(a1v.x + a1v.y, g2s, bb2s), 0.0f);
        }
        __syncthreads();
    }

    // ---- stage 3 (4 points): logits in registers from tbbuf ----
    float lg0[4], lg1[4];
    {
        float4 wb0 = *(const float4*)(cw + OFF_WBT + s2s * 8);
        float4 wb1 = *(const float4*)(cw + OFF_WBT + s2s * 8 + 4);
        f32x2 b0 = {wb0.x, wb0.y}, b1 = {wb0.z, wb0.w};
        f32x2 b2 = {wb1.x, wb1.y}, b3 = {wb1.z, wb1.w};
#pragma unroll
        for (int p = 0; p < 4; p++) {
            f32x2 acc0 = {cw[OFF_BW + s2s], 0.0f};
            f32x2 acc1 = acc0;
            float4 t00 = *((const float4*)&tbbuf[pt * 4 + p][s2n * 8]);
            float4 t01 = *((const float4*)&tbbuf[pt * 4 + p][s2n * 8 + 4]);
            float4 t10 = *((const float4*)&tbbuf[pt * 4 + p][(s2n + 8) * 8]);
            float4 t11 = *((const float4*)&tbbuf[pt * 4 + p][(s2n + 8) * 8 + 4]);
            f32x2 u0 = {t00.x, t00.y}, u1 = {t00.z, t00.w};
            f32x2 u2 = {t01.x, t01.y}, u3 = {t01.z, t01.w};
            f32x2 v0 = {t10.x, t10.y}, v1 = {t10.z, t10.w};
            f32x2 v2 = {t11.x, t11.y}, v3 = {t11.z, t11.w};
            acc0 += u0 * b0;  acc0 += u1 * b1;  acc0 += u2 * b2;  acc0 += u3 * b3;
            acc1 += v0 * b0;  acc1 += v1 * b1;  acc1 += v2 * b2;  acc1 += v3 * b3;
            lg0[p] = acc0.x + acc0.y;
            lg1[p] = acc1.x + acc1.y;
        }
    }

    // ---- stage 4 (4 points): softmax over n per channel t ----
#pragma unroll
    for (int p = 0; p < 4; p++) {
        float m = fmaxf(lg0[p], lg1[p]);
        m = fmaxf(m, __shfl_xor(m, 8, 64));
        m = fmaxf(m, __shfl_xor(m, 16, 64));
        m = fmaxf(m, __shfl_xor(m, 32, 64));
        float e0 = __expf(lg0[p] - m), e1 = __expf(lg1[p] - m);
        float s = e0 + e1;
        s += __shfl_xor(s, 8, 64);
        s += __shfl_xor(s, 16, 64);
        s += __shfl_xor(s, 32, 64);
        float inv = 1.0f / s;
        w2buf[pt * 4 + p][s2n * 8 + s2s]       = e0 * inv;
        w2buf[pt * 4 + p][(s2n + 8) * 8 + s2s] = e1 * inv;
    }
    __syncthreads();

    // ---- stage 5 (4 points): out[c] = sum_n pv[n] * w[n][c&7] ----
#pragma unroll
    for (int p = 0; p < 4; p++) {
        f32x2 ov = {0.0f, 0.0f};
#pragma unroll
        for (int n = 0; n < NSAMP; n += 2) {
            f32x2 pvp = {pv[p][n], pv[p][n + 1]};
            f32x2 wp  = {w2buf[pt * 4 + p][n * 8 + s2s], w2buf[pt * 4 + p][(n + 1) * 8 + s2s]};
            ov += pvp * wp;
        }
        float o = ov.x + ov.y;
        if (isf32) ((float*)OUT)[(size_t)(ib + p) * 64 + c] = o;
        else       ((__hip_bfloat16*)OUT)[(size_t)(ib + p) * 64 + c] = __float2bfloat16(o);
    }
}

// ---------------------------------------------------------------------------
extern "C" void kernel_launch(void* const* d_in, const int* in_sizes, int n_in,
                              void* d_out, int out_size, void* d_ws, size_t ws_size,
                              hipStream_t stream)
{
    const u16* p   = (const u16*)d_in[0];
    const u16* x   = (const u16*)d_in[1];
    const int* idx = (const int*)d_in[2];

    // workspace layout: cw 16KB + Q 25.6MB + KV 25.6MB ≈ 51.2 MB
    float* cw = (float*)d_ws;                   // 16 KB
    float* Q  = cw + CW_PAD;                    // N*64 f32 = 25.6 MB
    u32*   KV = (u32*)(Q + (size_t)N_PTS * 64); // N*64 u32 = 25.6 MB

    qkv_mfma_kernel<<<625, 256, 0, stream>>>(
        x,
        d_in[3],  d_in[4],  d_in[5],  d_in[6],  d_in[7],  d_in[8],
        d_in[9],  d_in[10], d_in[11], d_in[12], d_in[13], d_in[14],
        d_in[15], d_in[16], d_in[17], d_in[18], d_in[19], d_in[20],
        d_in[21], d_in[22], cw, Q, KV);                    // 625*10*16 = 100000
    attn_kernel<<<N_PTS / 16, 256, 0, stream>>>(p, idx, x, cw, Q, KV, d_out);
}

// Round 13
// 315.874 us; speedup vs baseline: 1.4954x; 1.4954x over previous
//
#include <hip/hip_runtime.h>
#include <hip/hip_bf16.h>

typedef unsigned int u32;
typedef unsigned short u16;
typedef __attribute__((ext_vector_type(8))) short short8;   // 8 bf16 (4 VGPRs)
typedef __attribute__((ext_vector_type(4))) float f32x4;    // MFMA C/D
typedef __attribute__((ext_vector_type(2))) float f32x2;    // v_pk_fma_f32 operand
typedef __attribute__((ext_vector_type(4))) u32 u32x4;

#define N_PTS 100000
#define NSAMP 16

__device__ __forceinline__ float lo2f(u32 u){ return __uint_as_float(u << 16); }
__device__ __forceinline__ float hi2f(u32 u){ return __uint_as_float(u & 0xffff0000u); }
__device__ __forceinline__ float us2f(u16 u){ return __uint_as_float(((u32)u) << 16); }

// round-to-nearest-even f32 -> bf16 bits (finite values only)
__device__ __forceinline__ u16 f2bf(float f) {
    u32 u = __float_as_uint(f);
    return (u16)((u + 0x7fffu + ((u >> 16) & 1u)) >> 16);
}
__device__ __forceinline__ u32 pack2(float k, float v) {
    return (u32)f2bf(k) | ((u32)f2bf(v) << 16);
}

// wave-local LDS RAW fence. The "memory" clobber ALSO pins global loads
// above it (they cannot sink past) — R4/R11-proven mechanism that keeps
// the whole gather burst issued up-front.
#define WAVE_LDS_FENCE() asm volatile("s_waitcnt lgkmcnt(0)" ::: "memory")

// Runtime input-dtype probe (must be called by ALL threads of the block).
__device__ __forceinline__ bool detect_f32(const u16* __restrict__ xprobe) {
    float f = us2f(xprobe[(threadIdx.x & 63) * 2]);
    int cnt = __syncthreads_count(fabsf(f) > 1024.0f ? 1 : 0);
    return cnt >= 8;
}

// generic raw-weight element load (fp32 or bf16 source)
__device__ __forceinline__ float rawf(const void* s, int i, bool isf32) {
    return isf32 ? ((const float*)s)[i] : us2f(((const u16*)s)[i]);
}

// canonical fp32 weight-block offsets (floats) — written by qkv block 0,
// consumed by attn (stream-ordered).
#define OFF_WP1  0
#define OFF_BP1  12
#define OFF_GP   16
#define OFF_BP   20
#define OFF_WP2  24
#define OFF_BP2  216
#define OFF_G1   280
#define OFF_BB1  344
#define OFF_BA   408
#define OFF_G2   416
#define OFF_BB2  424
#define OFF_BW   432
#define OFF_WAT  448     /* WaT[s][c] : 8 x 64 f32 (transposed Wa) */
#define OFF_WBT  960     /* WbT[t][s] : 8 x 8  f32 (transposed Wb) */
#define CW_PAD   4096    /* pad to 16 KB of floats */

// ---------------------------------------------------------------------------
// K1: MFMA QKV projection + (block 0) attn-weight canonicalization.
// Round-13: SWAPPED MFMA operands -> D holds output TRANSPOSED in lane
// space: lane l owns row M0+(l&15), cols w*16+g*4..+3 -> one float4 store
// for Q and one uint4 for KV per tile (was 8 scalar dwords). Frags are
// byte-identical to R11/R12 (k-map cancellation unchanged); only the call
// order and epilogue change.
// ---------------------------------------------------------------------------
#define QKV_TPB 10
__global__ __launch_bounds__(256) void qkv_mfma_kernel(
    const u16* __restrict__ xraw,
    const void* s0,  const void* s1,  const void* s2,  const void* s3,
    const void* s4,  const void* s5,  const void* s6,  const void* s7,
    const void* s8,  const void* s9,  const void* s10, const void* s11,
    const void* s12, const void* s13, const void* s14, const void* s15,
    const void* s16, const void* s17, const void* s18, const void* s19,
    float* __restrict__ cw,
    float* __restrict__ Q, u32* __restrict__ KV)
{
    bool isf32 = detect_f32(xraw);
    const int w   = threadIdx.x >> 6;
    const int l   = threadIdx.x & 63;
    const int col = l & 15;
    const int g   = l >> 4;

    // ---- block 0: write attn's canonical weight block ----
    if (blockIdx.x == 0) {
        const void* srcs[12] = {s6,s7,s8,s9,s10,s11,s12,s13,s15,s16,s17,s19};
        const int   sizes[12]= {9,3,3,3,192,64,64,64,8,8,8,8};
        const int   offs[12] = {OFF_WP1,OFF_BP1,OFF_GP,OFF_BP,OFF_WP2,OFF_BP2,
                                OFF_G1,OFF_BB1,OFF_BA,OFF_G2,OFF_BB2,OFF_BW};
        int tid = threadIdx.x;
        for (int a = 0; a < 12; a++)
            for (int k = tid; k < sizes[a]; k += 256)
                cw[offs[a] + k] = rawf(srcs[a], k, isf32);
        // WaT[s][c] = Wa[c][s] ; WbT[t][s] = Wb[s][t]
        for (int t = tid; t < 512 + 64; t += 256) {
            if (t < 512) {
                int s = t >> 6, cc = t & 63;
                cw[OFF_WAT + s * 64 + cc] = rawf(s14, cc * 8 + s, isf32);
            } else {
                int r = t - 512;
                int tt = r >> 3, ss = r & 7;
                cw[OFF_WBT + tt * 8 + ss] = rawf(s18, ss * 8 + tt, isf32);
            }
        }
    }

    // ---- build W fragments in registers: hi/lo bf16 planes (same as R11) ----
    const void* wsrc[3] = {s0, s2, s4};
    short8 bh[3][2], bl[3][2];
#pragma unroll
    for (int m = 0; m < 3; m++)
#pragma unroll
        for (int kh = 0; kh < 2; kh++)
#pragma unroll
            for (int j = 0; j < 8; j++) {
                float wv_ = rawf(wsrc[m], (kh * 32 + g * 8 + j) * 64 + w * 16 + col, isf32);
                u16 hb = f2bf(wv_);
                bh[m][kh][j] = (short)hb;
                bl[m][kh][j] = (short)f2bf(wv_ - us2f(hb));
            }
    // per-reg bias (D row m = g*4+r -> weight col w*16+g*4+r), loop-invariant
    float bq[4], bk[4], bv[4];
#pragma unroll
    for (int r = 0; r < 4; r++) {
        bq[r] = rawf(s1, w * 16 + g * 4 + r, isf32);
        bk[r] = rawf(s3, w * 16 + g * 4 + r, isf32);
        bv[r] = rawf(s5, w * 16 + g * 4 + r, isf32);
    }

#define LOAD_A(IT, AH, AL)                                                        \
    {                                                                             \
        const int M0_ = (blockIdx.x * QKV_TPB + (IT)) * 16;                       \
        if (isf32) {                                                              \
            const float4* xf = (const float4*)xraw;                               \
            _Pragma("unroll")                                                     \
            for (int kh = 0; kh < 2; kh++) {                                      \
                float4 f0 = xf[(size_t)(M0_ + col) * 16 + kh * 8 + g * 2];        \
                float4 f1 = xf[(size_t)(M0_ + col) * 16 + kh * 8 + g * 2 + 1];    \
                float ff[8] = {f0.x, f0.y, f0.z, f0.w, f1.x, f1.y, f1.z, f1.w};   \
                _Pragma("unroll")                                                 \
                for (int j = 0; j < 8; j++) {                                     \
                    u16 hb_ = f2bf(ff[j]);                                        \
                    AH[kh][j] = (short)hb_;                                       \
                    AL[kh][j] = (short)f2bf(ff[j] - us2f(hb_));                   \
                }                                                                 \
            }                                                                     \
        } else {                                                                  \
            const short8* xb = (const short8*)xraw;                               \
            _Pragma("unroll")                                                     \
            for (int kh = 0; kh < 2; kh++)                                        \
                AH[kh] = xb[(size_t)(M0_ + col) * 8 + kh * 4 + g];                \
        }                                                                         \
    }

    short8 ahA[2], alA[2], ahB[2], alB[2];
    LOAD_A(0, ahA, alA);

#pragma unroll
    for (int it = 0; it < QKV_TPB; it++) {
        short8 (&ah)[2] = (it & 1) ? ahB : ahA;
        short8 (&al)[2] = (it & 1) ? alB : alA;
        short8 (&ahN)[2] = (it & 1) ? ahA : ahB;
        short8 (&alN)[2] = (it & 1) ? alA : alB;
        if (it + 1 < QKV_TPB) LOAD_A(it + 1, ahN, alN);

        const int M0 = (blockIdx.x * QKV_TPB + it) * 16;
        f32x4 aQ = {bq[0], bq[1], bq[2], bq[3]};
        f32x4 aK = {bk[0], bk[1], bk[2], bk[3]};
        f32x4 aV = {bv[0], bv[1], bv[2], bv[3]};

        // SWAPPED operand order: D = Wfrag . xfrag  -> D[m=W col][n=x row]
#pragma unroll
        for (int kh = 0; kh < 2; kh++) {
            aQ = __builtin_amdgcn_mfma_f32_16x16x32_bf16(bh[0][kh], ah[kh], aQ, 0, 0, 0);
            aK = __builtin_amdgcn_mfma_f32_16x16x32_bf16(bh[1][kh], ah[kh], aK, 0, 0, 0);
            aV = __builtin_amdgcn_mfma_f32_16x16x32_bf16(bh[2][kh], ah[kh], aV, 0, 0, 0);
            aQ = __builtin_amdgcn_mfma_f32_16x16x32_bf16(bl[0][kh], ah[kh], aQ, 0, 0, 0);
            aK = __builtin_amdgcn_mfma_f32_16x16x32_bf16(bl[1][kh], ah[kh], aK, 0, 0, 0);
            aV = __builtin_amdgcn_mfma_f32_16x16x32_bf16(bl[2][kh], ah[kh], aV, 0, 0, 0);
            if (isf32) {
                aQ = __builtin_amdgcn_mfma_f32_16x16x32_bf16(bh[0][kh], al[kh], aQ, 0, 0, 0);
                aK = __builtin_amdgcn_mfma_f32_16x16x32_bf16(bh[1][kh], al[kh], aK, 0, 0, 0);
                aV = __builtin_amdgcn_mfma_f32_16x16x32_bf16(bh[2][kh], al[kh], aV, 0, 0, 0);
            }
        }

        // ---- vectorized epilogue: lane owns row M0+(l&15), cols w*16+g*4.. ----
        {
            const int row = M0 + col;                 // col == l&15
            float4 qv = {aQ[0], aQ[1], aQ[2], aQ[3]};
            *(float4*)&Q[(size_t)row * 64 + w * 16 + g * 4] = qv;
            u32x4 kvv = {pack2(aK[0], aV[0]), pack2(aK[1], aV[1]),
                         pack2(aK[2], aV[2]), pack2(aK[3], aV[3])};
            *(u32x4*)&KV[(size_t)row * 64 + w * 16 + g * 4] = kvv;
        }
    }
#undef LOAD_A
}

// ---------------------------------------------------------------------------
// K2: fused attention — round 11 VERBATIM (best proven: 185 us, VGPR 80,
// occ 33%). Two points per wave; 32 gathers pinned in one burst by the
// lgkmcnt+memory fence; __launch_bounds__(256,3).
// ---------------------------------------------------------------------------
__global__ __launch_bounds__(256, 3) void attn_kernel(
    const u16* __restrict__ P, const int* __restrict__ IDX,
    const u16* __restrict__ xprobe, const float* __restrict__ cw,
    const float* __restrict__ Q, const u32* __restrict__ KV,
    void* __restrict__ OUT)
{
    __shared__ __align__(16) float wvbuf[8][NSAMP * 68];  // relu(bn1(w)), stride 68
    __shared__ __align__(16) float tbbuf[8][NSAMP * 8];   // relu(bn2(.@Wa+ba))
    __shared__ __align__(16) float w2buf[8][NSAMP * 8];   // softmax weights
    __shared__ __align__(16) float hbuf[8][NSAMP * 4];    // h[n][d], d<3 used

    bool isf32 = detect_f32(xprobe);

    const int pt  = threadIdx.x >> 6;
    const int c   = threadIdx.x & 63;
    const int i0  = blockIdx.x * 8 + pt * 2;   // grid*8 == N_PTS exactly
    const int i1  = i0 + 1;
    const int sl0 = pt * 2, sl1 = sl0 + 1;     // wave-owned LDS slices
    const float rs = 1.0f / sqrtf(1.0f + 1e-5f);

    // ---- burst: indices + 32 KV gathers + Q + P, all before the fence ----
    const int jv0 = IDX[(size_t)i0 * NSAMP + (c & 15)];
    const int jv1 = IDX[(size_t)i1 * NSAMP + (c & 15)];

    u32 kv0[NSAMP], kv1[NSAMP];
    const u32* KVc = KV + c;
#pragma unroll
    for (int n = 0; n < NSAMP; n++) {
        int j = __builtin_amdgcn_readlane(jv0, n);   // SGPR -> SALU addressing
        kv0[n] = KVc[(size_t)j << 6];
    }
#pragma unroll
    for (int n = 0; n < NSAMP; n++) {
        int j = __builtin_amdgcn_readlane(jv1, n);
        kv1[n] = KVc[(size_t)j << 6];
    }

    const float qq0 = Q[(size_t)i0 * 64 + c];
    const float qq1 = Q[(size_t)i1 * 64 + c];

    // ---- distributed h-MLP for both points: lane (n,d) = (c/3, c%3) ----
    const float* Pf = (const float*)P;
    const int n_p  = c / 3;
    const int d_p  = c - n_p * 3;
    const int np15 = n_p & 15;
    const int jp0  = __shfl(jv0, np15, 64);
    const int jp1  = __shfl(jv1, np15, 64);
    float pj0, pj1, pid0, pid1;
    if (isf32) {
        pj0 = Pf[(size_t)jp0 * 3 + d_p];  pid0 = Pf[(size_t)i0 * 3 + d_p];
        pj1 = Pf[(size_t)jp1 * 3 + d_p];  pid1 = Pf[(size_t)i1 * 3 + d_p];
    } else {
        pj0 = us2f(P[(size_t)jp0 * 3 + d_p]);  pid0 = us2f(P[(size_t)i0 * 3 + d_p]);
        pj1 = us2f(P[(size_t)jp1 * 3 + d_p]);  pid1 = us2f(P[(size_t)i1 * 3 + d_p]);
    }
    const float pr0 = pj0 - pid0, pr1 = pj1 - pid1;
    const int lb = np15 * 3;
    const float pA0 = __shfl(pr0, lb + 0, 64);
    const float pA1 = __shfl(pr0, lb + 1, 64);
    const float pA2 = __shfl(pr0, lb + 2, 64);
    const float pB0 = __shfl(pr1, lb + 0, 64);
    const float pB1 = __shfl(pr1, lb + 1, 64);
    const float pB2 = __shfl(pr1, lb + 2, 64);
    {
        float gd  = cw[OFF_GP + d_p] * rs;
        float w0s = cw[OFF_WP1 + 0 * 3 + d_p] * gd;
        float w1s = cw[OFF_WP1 + 1 * 3 + d_p] * gd;
        float w2s = cw[OFF_WP1 + 2 * 3 + d_p] * gd;
        float bs  = cw[OFF_BP1 + d_p] * gd + cw[OFF_BP + d_p];
        float hA = fmaxf(fmaf(pA2, w2s, fmaf(pA1, w1s, fmaf(pA0, w0s, bs))), 0.0f);
        float hB = fmaxf(fmaf(pB2, w2s, fmaf(pB1, w1s, fmaf(pB0, w0s, bs))), 0.0f);
        if (c < 48) {
            hbuf[sl0][np15 * 4 + d_p] = hA;
            hbuf[sl1][np15 * 4 + d_p] = hB;
        }
    }
    WAVE_LDS_FENCE();   // hbuf RAW (same wave) + pins the 32 gathers above

    // per-lane channel constants (L1-hot)
    const float wp2c0 = cw[OFF_WP2 + 0 * 64 + c];
    const float wp2c1 = cw[OFF_WP2 + 1 * 64 + c];
    const float wp2c2 = cw[OFF_WP2 + 2 * 64 + c];
    const float bp2c  = cw[OFF_BP2 + c];
    const float g1c   = cw[OFF_G1  + c] * rs;
    const float bb1c  = cw[OFF_BB1 + c];

    float pv0[NSAMP], pv1[NSAMP];

    // ---- stage 1 (both points): relation input into LDS; v+pe in regs ----
#pragma unroll
    for (int n = 0; n < NSAMP; n++) {
        float4 hb = *((const float4*)&hbuf[sl0][n * 4]);
        float pe = fmaf(hb.z, wp2c2, fmaf(hb.y, wp2c1, fmaf(hb.x, wp2c0, bp2c)));
        float kk = lo2f(kv0[n]);
        float vv = hi2f(kv0[n]);
        wvbuf[sl0][n * 68 + c] = fmaxf(fmaf(kk - qq0 + pe, g1c, bb1c), 0.0f);
        pv0[n] = vv + pe;
    }
#pragma unroll
    for (int n = 0; n < NSAMP; n++) {
        float4 hb = *((const float4*)&hbuf[sl1][n * 4]);
        float pe = fmaf(hb.z, wp2c2, fmaf(hb.y, wp2c1, fmaf(hb.x, wp2c0, bp2c)));
        float kk = lo2f(kv1[n]);
        float vv = hi2f(kv1[n]);
        wvbuf[sl1][n * 68 + c] = fmaxf(fmaf(kk - qq1 + pe, g1c, bb1c), 0.0f);
        pv1[n] = vv + pe;
    }
    __syncthreads();

    // ---- stage 2 (both points, merged reps, f32x2 packed) ----
    const int s2s = c & 7, s2n = c >> 3;
    f32x2 aA0 = {cw[OFF_BA + s2s], 0.0f};
    f32x2 aA1 = aA0, aB0 = aA0, aB1 = aA0;
    const float4* waT4 = (const float4*)(cw + OFF_WAT + s2s * 64);
#pragma unroll
    for (int c4 = 0; c4 < 16; c4++) {
        float4 wa = waT4[c4];
        f32x2 waA = {wa.x, wa.y}, waB = {wa.z, wa.w};
        float4 rA0 = *((const float4*)&wvbuf[sl0][s2n * 68 + c4 * 4]);
        float4 rA1 = *((const float4*)&wvbuf[sl0][(s2n + 8) * 68 + c4 * 4]);
        float4 rB0 = *((const float4*)&wvbuf[sl1][s2n * 68 + c4 * 4]);
        float4 rB1 = *((const float4*)&wvbuf[sl1][(s2n + 8) * 68 + c4 * 4]);
        f32x2 tA0a = {rA0.x, rA0.y}, tA0b = {rA0.z, rA0.w};
        f32x2 tA1a = {rA1.x, rA1.y}, tA1b = {rA1.z, rA1.w};
        f32x2 tB0a = {rB0.x, rB0.y}, tB0b = {rB0.z, rB0.w};
        f32x2 tB1a = {rB1.x, rB1.y}, tB1b = {rB1.z, rB1.w};
        aA0 += tA0a * waA;  aA0 += tA0b * waB;
        aA1 += tA1a * waA;  aA1 += tA1b * waB;
        aB0 += tB0a * waA;  aB0 += tB0b * waB;
        aB1 += tB1a * waA;  aB1 += tB1b * waB;
    }
    {
        float g2s = cw[OFF_G2 + s2s] * rs, bb2s = cw[OFF_BB2 + s2s];
        tbbuf[sl0][s2n * 8 + s2s]       = fmaxf(fmaf(aA0.x + aA0.y, g2s, bb2s), 0.0f);
        tbbuf[sl0][(s2n + 8) * 8 + s2s] = fmaxf(fmaf(aA1.x + aA1.y, g2s, bb2s), 0.0f);
        tbbuf[sl1][s2n * 8 + s2s]       = fmaxf(fmaf(aB0.x + aB0.y, g2s, bb2s), 0.0f);
        tbbuf[sl1][(s2n + 8) * 8 + s2s] = fmaxf(fmaf(aB1.x + aB1.y, g2s, bb2s), 0.0f);
    }
    __syncthreads();

    // ---- stage 3 (both points): logits in registers ----
    f32x2 wA0 = {cw[OFF_BW + s2s], 0.0f};
    f32x2 wA1 = wA0, wB0 = wA0, wB1 = wA0;
    {
        float4 wb0 = *(const float4*)(cw + OFF_WBT + s2s * 8);
        float4 wb1 = *(const float4*)(cw + OFF_WBT + s2s * 8 + 4);
        f32x2 b0 = {wb0.x, wb0.y}, b1 = {wb0.z, wb0.w};
        f32x2 b2 = {wb1.x, wb1.y}, b3 = {wb1.z, wb1.w};
#define ACC_LOGIT(ACC, SL, ROW)                                                   \
        {                                                                         \
            float4 t0_ = *((const float4*)&tbbuf[SL][(ROW) * 8]);                 \
            float4 t1_ = *((const float4*)&tbbuf[SL][(ROW) * 8 + 4]);             \
            f32x2 u0_ = {t0_.x, t0_.y}, u1_ = {t0_.z, t0_.w};                     \
            f32x2 u2_ = {t1_.x, t1_.y}, u3_ = {t1_.z, t1_.w};                     \
            ACC += u0_ * b0;  ACC += u1_ * b1;  ACC += u2_ * b2;  ACC += u3_ * b3;\
        }
        ACC_LOGIT(wA0, sl0, s2n)
        ACC_LOGIT(wA1, sl0, s2n + 8)
        ACC_LOGIT(wB0, sl1, s2n)
        ACC_LOGIT(wB1, sl1, s2n + 8)
#undef ACC_LOGIT
    }
    float lA0 = wA0.x + wA0.y, lA1 = wA1.x + wA1.y;
    float lB0 = wB0.x + wB0.y, lB1 = wB1.x + wB1.y;

    // ---- stage 4: softmax per point over n (lanes share s via xor tree) ----
    {
        float m0 = fmaxf(lA0, lA1);
        m0 = fmaxf(m0, __shfl_xor(m0, 8, 64));
        m0 = fmaxf(m0, __shfl_xor(m0, 16, 64));
        m0 = fmaxf(m0, __shfl_xor(m0, 32, 64));
        float e00 = __expf(lA0 - m0), e01 = __expf(lA1 - m0);
        float s0 = e00 + e01;
        s0 += __shfl_xor(s0, 8, 64);
        s0 += __shfl_xor(s0, 16, 64);
        s0 += __shfl_xor(s0, 32, 64);
        float inv0 = 1.0f / s0;
        w2buf[sl0][s2n * 8 + s2s]       = e00 * inv0;
        w2buf[sl0][(s2n + 8) * 8 + s2s] = e01 * inv0;

        float m1 = fmaxf(lB0, lB1);
        m1 = fmaxf(m1, __shfl_xor(m1, 8, 64));
        m1 = fmaxf(m1, __shfl_xor(m1, 16, 64));
        m1 = fmaxf(m1, __shfl_xor(m1, 32, 64));
        float e10 = __expf(lB0 - m1), e11 = __expf(lB1 - m1);
        float s1 = e10 + e11;
        s1 += __shfl_xor(s1, 8, 64);
        s1 += __shfl_xor(s1, 16, 64);
        s1 += __shfl_xor(s1, 32, 64);
        float inv1 = 1.0f / s1;
        w2buf[sl1][s2n * 8 + s2s]       = e10 * inv1;
        w2buf[sl1][(s2n + 8) * 8 + s2s] = e11 * inv1;
    }
    __syncthreads();

    // ---- stage 5 (both points): out[c] = sum_n pv[n] * w[n][c&7] ----
    f32x2 ov0 = {0.0f, 0.0f}, ov1 = {0.0f, 0.0f};
#pragma unroll
    for (int n = 0; n < NSAMP; n += 2) {
        f32x2 p0 = {pv0[n], pv0[n + 1]};
        f32x2 w0 = {w2buf[sl0][n * 8 + s2s], w2buf[sl0][(n + 1) * 8 + s2s]};
        f32x2 p1 = {pv1[n], pv1[n + 1]};
        f32x2 w1 = {w2buf[sl1][n * 8 + s2s], w2buf[sl1][(n + 1) * 8 + s2s]};
        ov0 += p0 * w0;
        ov1 += p1 * w1;
    }
    float o0 = ov0.x + ov0.y;
    float o1 = ov1.x + ov1.y;
    if (isf32) {
        ((float*)OUT)[(size_t)i0 * 64 + c] = o0;
        ((float*)OUT)[(size_t)i1 * 64 + c] = o1;
    } else {
        ((__hip_bfloat16*)OUT)[(size_t)i0 * 64 + c] = __float2bfloat16(o0);
        ((__hip_bfloat16*)OUT)[(size_t)i1 * 64 + c] = __float2bfloat16(o1);
    }
}

// ---------------------------------------------------------------------------
extern "C" void kernel_launch(void* const* d_in, const int* in_sizes, int n_in,
                              void* d_out, int out_size, void* d_ws, size_t ws_size,
                              hipStream_t stream)
{
    const u16* p   = (const u16*)d_in[0];
    const u16* x   = (const u16*)d_in[1];
    const int* idx = (const int*)d_in[2];

    // workspace layout: cw 16KB + Q 25.6MB + KV 25.6MB ≈ 51.2 MB
    float* cw = (float*)d_ws;                   // 16 KB
    float* Q  = cw + CW_PAD;                    // N*64 f32 = 25.6 MB
    u32*   KV = (u32*)(Q + (size_t)N_PTS * 64); // N*64 u32 = 25.6 MB

    qkv_mfma_kernel<<<625, 256, 0, stream>>>(
        x,
        d_in[3],  d_in[4],  d_in[5],  d_in[6],  d_in[7],  d_in[8],
        d_in[9],  d_in[10], d_in[11], d_in[12], d_in[13], d_in[14],
        d_in[15], d_in[16], d_in[17], d_in[18], d_in[19], d_in[20],
        d_in[21], d_in[22], cw, Q, KV);                    // 625*10*16 = 100000
    attn_kernel<<<N_PTS / 8, 256, 0, stream>>>(p, idx, x, cw, Q, KV, d_out);
}

// Round 14
// 281.536 us; speedup vs baseline: 1.6778x; 1.1220x over previous
//
#include <hip/hip_runtime.h>
#include <hip/hip_bf16.h>

typedef unsigned int u32;
typedef unsigned short u16;
typedef __attribute__((ext_vector_type(8))) short short8;   // 8 bf16 (4 VGPRs)
typedef __attribute__((ext_vector_type(4))) float f32x4;    // MFMA C/D
typedef __attribute__((ext_vector_type(2))) float f32x2;    // v_pk_fma_f32 operand
typedef __attribute__((ext_vector_type(4))) u32 u32x4;

#define N_PTS 100000
#define NSAMP 16

__device__ __forceinline__ float lo2f(u32 u){ return __uint_as_float(u << 16); }
__device__ __forceinline__ float hi2f(u32 u){ return __uint_as_float(u & 0xffff0000u); }
__device__ __forceinline__ float us2f(u16 u){ return __uint_as_float(((u32)u) << 16); }

// round-to-nearest-even f32 -> bf16 bits (finite values only)
__device__ __forceinline__ u16 f2bf(float f) {
    u32 u = __float_as_uint(f);
    return (u16)((u + 0x7fffu + ((u >> 16) & 1u)) >> 16);
}
__device__ __forceinline__ u32 pack2(float k, float v) {
    return (u32)f2bf(k) | ((u32)f2bf(v) << 16);
}

// wave-local LDS RAW fence. The "memory" clobber ALSO pins global loads
// above it (they cannot sink past) — R4/R11-proven mechanism that keeps
// the whole gather burst issued up-front.
#define WAVE_LDS_FENCE() asm volatile("s_waitcnt lgkmcnt(0)" ::: "memory")

// Runtime input-dtype probe (must be called by ALL threads of the block).
__device__ __forceinline__ bool detect_f32(const u16* __restrict__ xprobe) {
    float f = us2f(xprobe[(threadIdx.x & 63) * 2]);
    int cnt = __syncthreads_count(fabsf(f) > 1024.0f ? 1 : 0);
    return cnt >= 8;
}

// generic raw-weight element load (fp32 or bf16 source)
__device__ __forceinline__ float rawf(const void* s, int i, bool isf32) {
    return isf32 ? ((const float*)s)[i] : us2f(((const u16*)s)[i]);
}

// canonical fp32 weight-block offsets (floats) — written by qkv block 0,
// consumed by attn (stream-ordered).
#define OFF_WP1  0
#define OFF_BP1  12
#define OFF_GP   16
#define OFF_BP   20
#define OFF_WP2  24
#define OFF_BP2  216
#define OFF_G1   280
#define OFF_BB1  344
#define OFF_BA   408
#define OFF_G2   416
#define OFF_BB2  424
#define OFF_BW   432
#define OFF_WAT  448     /* WaT[s][c] : 8 x 64 f32 (transposed Wa) */
#define OFF_WBT  960     /* WbT[t][s] : 8 x 8  f32 (transposed Wb) */
#define CW_PAD   4096    /* pad to 16 KB of floats */

// ---------------------------------------------------------------------------
// K1: MFMA QKV projection + (block 0) attn-weight canonicalization.
// (round-13 version: swapped operands + vectorized float4/uint4 epilogue —
// passing; non-attn residual proved insensitive to qkv shape, so frozen.)
// ---------------------------------------------------------------------------
#define QKV_TPB 10
__global__ __launch_bounds__(256) void qkv_mfma_kernel(
    const u16* __restrict__ xraw,
    const void* s0,  const void* s1,  const void* s2,  const void* s3,
    const void* s4,  const void* s5,  const void* s6,  const void* s7,
    const void* s8,  const void* s9,  const void* s10, const void* s11,
    const void* s12, const void* s13, const void* s14, const void* s15,
    const void* s16, const void* s17, const void* s18, const void* s19,
    float* __restrict__ cw,
    float* __restrict__ Q, u32* __restrict__ KV)
{
    bool isf32 = detect_f32(xraw);
    const int w   = threadIdx.x >> 6;
    const int l   = threadIdx.x & 63;
    const int col = l & 15;
    const int g   = l >> 4;

    // ---- block 0: write attn's canonical weight block ----
    if (blockIdx.x == 0) {
        const void* srcs[12] = {s6,s7,s8,s9,s10,s11,s12,s13,s15,s16,s17,s19};
        const int   sizes[12]= {9,3,3,3,192,64,64,64,8,8,8,8};
        const int   offs[12] = {OFF_WP1,OFF_BP1,OFF_GP,OFF_BP,OFF_WP2,OFF_BP2,
                                OFF_G1,OFF_BB1,OFF_BA,OFF_G2,OFF_BB2,OFF_BW};
        int tid = threadIdx.x;
        for (int a = 0; a < 12; a++)
            for (int k = tid; k < sizes[a]; k += 256)
                cw[offs[a] + k] = rawf(srcs[a], k, isf32);
        // WaT[s][c] = Wa[c][s] ; WbT[t][s] = Wb[s][t]
        for (int t = tid; t < 512 + 64; t += 256) {
            if (t < 512) {
                int s = t >> 6, cc = t & 63;
                cw[OFF_WAT + s * 64 + cc] = rawf(s14, cc * 8 + s, isf32);
            } else {
                int r = t - 512;
                int tt = r >> 3, ss = r & 7;
                cw[OFF_WBT + tt * 8 + ss] = rawf(s18, ss * 8 + tt, isf32);
            }
        }
    }

    // ---- build W fragments in registers: hi/lo bf16 planes ----
    const void* wsrc[3] = {s0, s2, s4};
    short8 bh[3][2], bl[3][2];
#pragma unroll
    for (int m = 0; m < 3; m++)
#pragma unroll
        for (int kh = 0; kh < 2; kh++)
#pragma unroll
            for (int j = 0; j < 8; j++) {
                float wv_ = rawf(wsrc[m], (kh * 32 + g * 8 + j) * 64 + w * 16 + col, isf32);
                u16 hb = f2bf(wv_);
                bh[m][kh][j] = (short)hb;
                bl[m][kh][j] = (short)f2bf(wv_ - us2f(hb));
            }
    // per-reg bias (D row m = g*4+r -> weight col w*16+g*4+r), loop-invariant
    float bq[4], bk[4], bv[4];
#pragma unroll
    for (int r = 0; r < 4; r++) {
        bq[r] = rawf(s1, w * 16 + g * 4 + r, isf32);
        bk[r] = rawf(s3, w * 16 + g * 4 + r, isf32);
        bv[r] = rawf(s5, w * 16 + g * 4 + r, isf32);
    }

#define LOAD_A(IT, AH, AL)                                                        \
    {                                                                             \
        const int M0_ = (blockIdx.x * QKV_TPB + (IT)) * 16;                       \
        if (isf32) {                                                              \
            const float4* xf = (const float4*)xraw;                               \
            _Pragma("unroll")                                                     \
            for (int kh = 0; kh < 2; kh++) {                                      \
                float4 f0 = xf[(size_t)(M0_ + col) * 16 + kh * 8 + g * 2];        \
                float4 f1 = xf[(size_t)(M0_ + col) * 16 + kh * 8 + g * 2 + 1];    \
                float ff[8] = {f0.x, f0.y, f0.z, f0.w, f1.x, f1.y, f1.z, f1.w};   \
                _Pragma("unroll")                                                 \
                for (int j = 0; j < 8; j++) {                                     \
                    u16 hb_ = f2bf(ff[j]);                                        \
                    AH[kh][j] = (short)hb_;                                       \
                    AL[kh][j] = (short)f2bf(ff[j] - us2f(hb_));                   \
                }                                                                 \
            }                                                                     \
        } else {                                                                  \
            const short8* xb = (const short8*)xraw;                               \
            _Pragma("unroll")                                                     \
            for (int kh = 0; kh < 2; kh++)                                        \
                AH[kh] = xb[(size_t)(M0_ + col) * 8 + kh * 4 + g];                \
        }                                                                         \
    }

    short8 ahA[2], alA[2], ahB[2], alB[2];
    LOAD_A(0, ahA, alA);

#pragma unroll
    for (int it = 0; it < QKV_TPB; it++) {
        short8 (&ah)[2] = (it & 1) ? ahB : ahA;
        short8 (&al)[2] = (it & 1) ? alB : alA;
        short8 (&ahN)[2] = (it & 1) ? ahA : ahB;
        short8 (&alN)[2] = (it & 1) ? alA : alB;
        if (it + 1 < QKV_TPB) LOAD_A(it + 1, ahN, alN);

        const int M0 = (blockIdx.x * QKV_TPB + it) * 16;
        f32x4 aQ = {bq[0], bq[1], bq[2], bq[3]};
        f32x4 aK = {bk[0], bk[1], bk[2], bk[3]};
        f32x4 aV = {bv[0], bv[1], bv[2], bv[3]};

        // SWAPPED operand order: D = Wfrag . xfrag  -> D[m=W col][n=x row]
#pragma unroll
        for (int kh = 0; kh < 2; kh++) {
            aQ = __builtin_amdgcn_mfma_f32_16x16x32_bf16(bh[0][kh], ah[kh], aQ, 0, 0, 0);
            aK = __builtin_amdgcn_mfma_f32_16x16x32_bf16(bh[1][kh], ah[kh], aK, 0, 0, 0);
            aV = __builtin_amdgcn_mfma_f32_16x16x32_bf16(bh[2][kh], ah[kh], aV, 0, 0, 0);
            aQ = __builtin_amdgcn_mfma_f32_16x16x32_bf16(bl[0][kh], ah[kh], aQ, 0, 0, 0);
            aK = __builtin_amdgcn_mfma_f32_16x16x32_bf16(bl[1][kh], ah[kh], aK, 0, 0, 0);
            aV = __builtin_amdgcn_mfma_f32_16x16x32_bf16(bl[2][kh], ah[kh], aV, 0, 0, 0);
            if (isf32) {
                aQ = __builtin_amdgcn_mfma_f32_16x16x32_bf16(bh[0][kh], al[kh], aQ, 0, 0, 0);
                aK = __builtin_amdgcn_mfma_f32_16x16x32_bf16(bh[1][kh], al[kh], aK, 0, 0, 0);
                aV = __builtin_amdgcn_mfma_f32_16x16x32_bf16(bh[2][kh], al[kh], aV, 0, 0, 0);
            }
        }

        // ---- vectorized epilogue: lane owns row M0+(l&15), cols w*16+g*4.. ----
        {
            const int row = M0 + col;                 // col == l&15
            float4 qv = {aQ[0], aQ[1], aQ[2], aQ[3]};
            *(float4*)&Q[(size_t)row * 64 + w * 16 + g * 4] = qv;
            u32x4 kvv = {pack2(aK[0], aV[0]), pack2(aK[1], aV[1]),
                         pack2(aK[2], aV[2]), pack2(aK[3], aV[3])};
            *(u32x4*)&KV[(size_t)row * 64 + w * 16 + g * 4] = kvv;
        }
    }
#undef LOAD_A
}

// ---------------------------------------------------------------------------
// K2: fused attention — round 14 = round 11 with LDS lifetime overlays:
//   - hbuf  (dead after stage 1) lives inside tbbuf (born stage 2)
//   - w2buf (born stage 4)       lives inside wvbuf (dead after stage 2)
// Declared LDS 45.1 -> 38.9 KB  => 4 blocks/CU = 16 waves/CU (was 3/12).
// Every instruction of the proven R11 kernel is otherwise unchanged; the
// existing barriers order the overlapping lifetimes. __launch_bounds__
// (256,4) caps VGPR at 128 (we use 80).
// ---------------------------------------------------------------------------
__global__ __launch_bounds__(256, 4) void attn_kernel(
    const u16* __restrict__ P, const int* __restrict__ IDX,
    const u16* __restrict__ xprobe, const float* __restrict__ cw,
    const float* __restrict__ Q, const u32* __restrict__ KV,
    void* __restrict__ OUT)
{
    __shared__ __align__(16) float wvbuf[8][NSAMP * 68];  // st1->st2; [0..127] reused as w2 in st4->st5
    __shared__ __align__(16) float tbbuf[8][NSAMP * 8];   // st2->st3; [0..63] reused as hbuf pre-st1

    bool isf32 = detect_f32(xprobe);

    const int pt  = threadIdx.x >> 6;
    const int c   = threadIdx.x & 63;
    const int i0  = blockIdx.x * 8 + pt * 2;   // grid*8 == N_PTS exactly
    const int i1  = i0 + 1;
    const int sl0 = pt * 2, sl1 = sl0 + 1;     // wave-owned LDS slices
    const float rs = 1.0f / sqrtf(1.0f + 1e-5f);

    // lifetime-overlay views (all wave-owned slices)
    float* hb0 = &tbbuf[sl0][0];   // hbuf for point 0 (64 floats)
    float* hb1 = &tbbuf[sl1][0];   // hbuf for point 1
    float* w20 = &wvbuf[sl0][0];   // softmax weights, point 0 (128 floats)
    float* w21 = &wvbuf[sl1][0];   // softmax weights, point 1

    // ---- burst: indices + 32 KV gathers + Q + P, all before the fence ----
    const int jv0 = IDX[(size_t)i0 * NSAMP + (c & 15)];
    const int jv1 = IDX[(size_t)i1 * NSAMP + (c & 15)];

    u32 kv0[NSAMP], kv1[NSAMP];
    const u32* KVc = KV + c;
#pragma unroll
    for (int n = 0; n < NSAMP; n++) {
        int j = __builtin_amdgcn_readlane(jv0, n);   // SGPR -> SALU addressing
        kv0[n] = KVc[(size_t)j << 6];
    }
#pragma unroll
    for (int n = 0; n < NSAMP; n++) {
        int j = __builtin_amdgcn_readlane(jv1, n);
        kv1[n] = KVc[(size_t)j << 6];
    }

    const float qq0 = Q[(size_t)i0 * 64 + c];
    const float qq1 = Q[(size_t)i1 * 64 + c];

    // ---- distributed h-MLP for both points: lane (n,d) = (c/3, c%3) ----
    const float* Pf = (const float*)P;
    const int n_p  = c / 3;
    const int d_p  = c - n_p * 3;
    const int np15 = n_p & 15;
    const int jp0  = __shfl(jv0, np15, 64);
    const int jp1  = __shfl(jv1, np15, 64);
    float pj0, pj1, pid0, pid1;
    if (isf32) {
        pj0 = Pf[(size_t)jp0 * 3 + d_p];  pid0 = Pf[(size_t)i0 * 3 + d_p];
        pj1 = Pf[(size_t)jp1 * 3 + d_p];  pid1 = Pf[(size_t)i1 * 3 + d_p];
    } else {
        pj0 = us2f(P[(size_t)jp0 * 3 + d_p]);  pid0 = us2f(P[(size_t)i0 * 3 + d_p]);
        pj1 = us2f(P[(size_t)jp1 * 3 + d_p]);  pid1 = us2f(P[(size_t)i1 * 3 + d_p]);
    }
    const float pr0 = pj0 - pid0, pr1 = pj1 - pid1;
    const int lb = np15 * 3;
    const float pA0 = __shfl(pr0, lb + 0, 64);
    const float pA1 = __shfl(pr0, lb + 1, 64);
    const float pA2 = __shfl(pr0, lb + 2, 64);
    const float pB0 = __shfl(pr1, lb + 0, 64);
    const float pB1 = __shfl(pr1, lb + 1, 64);
    const float pB2 = __shfl(pr1, lb + 2, 64);
    {
        float gd  = cw[OFF_GP + d_p] * rs;
        float w0s = cw[OFF_WP1 + 0 * 3 + d_p] * gd;
        float w1s = cw[OFF_WP1 + 1 * 3 + d_p] * gd;
        float w2s = cw[OFF_WP1 + 2 * 3 + d_p] * gd;
        float bs  = cw[OFF_BP1 + d_p] * gd + cw[OFF_BP + d_p];
        float hA = fmaxf(fmaf(pA2, w2s, fmaf(pA1, w1s, fmaf(pA0, w0s, bs))), 0.0f);
        float hB = fmaxf(fmaf(pB2, w2s, fmaf(pB1, w1s, fmaf(pB0, w0s, bs))), 0.0f);
        if (c < 48) {
            hb0[np15 * 4 + d_p] = hA;
            hb1[np15 * 4 + d_p] = hB;
        }
    }
    WAVE_LDS_FENCE();   // hbuf RAW (same wave) + pins the 32 gathers above

    // per-lane channel constants (L1-hot)
    const float wp2c0 = cw[OFF_WP2 + 0 * 64 + c];
    const float wp2c1 = cw[OFF_WP2 + 1 * 64 + c];
    const float wp2c2 = cw[OFF_WP2 + 2 * 64 + c];
    const float bp2c  = cw[OFF_BP2 + c];
    const float g1c   = cw[OFF_G1  + c] * rs;
    const float bb1c  = cw[OFF_BB1 + c];

    float pv0[NSAMP], pv1[NSAMP];

    // ---- stage 1 (both points): relation input into LDS; v+pe in regs ----
#pragma unroll
    for (int n = 0; n < NSAMP; n++) {
        float4 hb = *((const float4*)&hb0[n * 4]);
        float pe = fmaf(hb.z, wp2c2, fmaf(hb.y, wp2c1, fmaf(hb.x, wp2c0, bp2c)));
        float kk = lo2f(kv0[n]);
        float vv = hi2f(kv0[n]);
        wvbuf[sl0][n * 68 + c] = fmaxf(fmaf(kk - qq0 + pe, g1c, bb1c), 0.0f);
        pv0[n] = vv + pe;
    }
#pragma unroll
    for (int n = 0; n < NSAMP; n++) {
        float4 hb = *((const float4*)&hb1[n * 4]);
        float pe = fmaf(hb.z, wp2c2, fmaf(hb.y, wp2c1, fmaf(hb.x, wp2c0, bp2c)));
        float kk = lo2f(kv1[n]);
        float vv = hi2f(kv1[n]);
        wvbuf[sl1][n * 68 + c] = fmaxf(fmaf(kk - qq1 + pe, g1c, bb1c), 0.0f);
        pv1[n] = vv + pe;
    }
    __syncthreads();

    // ---- stage 2 (both points, merged reps, f32x2 packed) ----
    const int s2s = c & 7, s2n = c >> 3;
    f32x2 aA0 = {cw[OFF_BA + s2s], 0.0f};
    f32x2 aA1 = aA0, aB0 = aA0, aB1 = aA0;
    const float4* waT4 = (const float4*)(cw + OFF_WAT + s2s * 64);
#pragma unroll
    for (int c4 = 0; c4 < 16; c4++) {
        float4 wa = waT4[c4];
        f32x2 waA = {wa.x, wa.y}, waB = {wa.z, wa.w};
        float4 rA0 = *((const float4*)&wvbuf[sl0][s2n * 68 + c4 * 4]);
        float4 rA1 = *((const float4*)&wvbuf[sl0][(s2n + 8) * 68 + c4 * 4]);
        float4 rB0 = *((const float4*)&wvbuf[sl1][s2n * 68 + c4 * 4]);
        float4 rB1 = *((const float4*)&wvbuf[sl1][(s2n + 8) * 68 + c4 * 4]);
        f32x2 tA0a = {rA0.x, rA0.y}, tA0b = {rA0.z, rA0.w};
        f32x2 tA1a = {rA1.x, rA1.y}, tA1b = {rA1.z, rA1.w};
        f32x2 tB0a = {rB0.x, rB0.y}, tB0b = {rB0.z, rB0.w};
        f32x2 tB1a = {rB1.x, rB1.y}, tB1b = {rB1.z, rB1.w};
        aA0 += tA0a * waA;  aA0 += tA0b * waB;
        aA1 += tA1a * waA;  aA1 += tA1b * waB;
        aB0 += tB0a * waA;  aB0 += tB0b * waB;
        aB1 += tB1a * waA;  aB1 += tB1b * waB;
    }
    {
        float g2s = cw[OFF_G2 + s2s] * rs, bb2s = cw[OFF_BB2 + s2s];
        tbbuf[sl0][s2n * 8 + s2s]       = fmaxf(fmaf(aA0.x + aA0.y, g2s, bb2s), 0.0f);
        tbbuf[sl0][(s2n + 8) * 8 + s2s] = fmaxf(fmaf(aA1.x + aA1.y, g2s, bb2s), 0.0f);
        tbbuf[sl1][s2n * 8 + s2s]       = fmaxf(fmaf(aB0.x + aB0.y, g2s, bb2s), 0.0f);
        tbbuf[sl1][(s2n + 8) * 8 + s2s] = fmaxf(fmaf(aB1.x + aB1.y, g2s, bb2s), 0.0f);
    }
    __syncthreads();

    // ---- stage 3 (both points): logits in registers ----
    f32x2 wA0 = {cw[OFF_BW + s2s], 0.0f};
    f32x2 wA1 = wA0, wB0 = wA0, wB1 = wA0;
    {
        float4 wb0 = *(const float4*)(cw + OFF_WBT + s2s * 8);
        float4 wb1 = *(const float4*)(cw + OFF_WBT + s2s * 8 + 4);
        f32x2 b0 = {wb0.x, wb0.y}, b1 = {wb0.z, wb0.w};
        f32x2 b2 = {wb1.x, wb1.y}, b3 = {wb1.z, wb1.w};
#define ACC_LOGIT(ACC, SL, ROW)                                                   \
        {                                                                         \
            float4 t0_ = *((const float4*)&tbbuf[SL][(ROW) * 8]);                 \
            float4 t1_ = *((const float4*)&tbbuf[SL][(ROW) * 8 + 4]);             \
            f32x2 u0_ = {t0_.x, t0_.y}, u1_ = {t0_.z, t0_.w};                     \
            f32x2 u2_ = {t1_.x, t1_.y}, u3_ = {t1_.z, t1_.w};                     \
            ACC += u0_ * b0;  ACC += u1_ * b1;  ACC += u2_ * b2;  ACC += u3_ * b3;\
        }
        ACC_LOGIT(wA0, sl0, s2n)
        ACC_LOGIT(wA1, sl0, s2n + 8)
        ACC_LOGIT(wB0, sl1, s2n)
        ACC_LOGIT(wB1, sl1, s2n + 8)
#undef ACC_LOGIT
    }
    float lA0 = wA0.x + wA0.y, lA1 = wA1.x + wA1.y;
    float lB0 = wB0.x + wB0.y, lB1 = wB1.x + wB1.y;

    // ---- stage 4: softmax per point over n; weights into w2 overlay ----
    {
        float m0 = fmaxf(lA0, lA1);
        m0 = fmaxf(m0, __shfl_xor(m0, 8, 64));
        m0 = fmaxf(m0, __shfl_xor(m0, 16, 64));
        m0 = fmaxf(m0, __shfl_xor(m0, 32, 64));
        float e00 = __expf(lA0 - m0), e01 = __expf(lA1 - m0);
        float s0 = e00 + e01;
        s0 += __shfl_xor(s0, 8, 64);
        s0 += __shfl_xor(s0, 16, 64);
        s0 += __shfl_xor(s0, 32, 64);
        float inv0 = 1.0f / s0;
        w20[s2n * 8 + s2s]       = e00 * inv0;
        w20[(s2n + 8) * 8 + s2s] = e01 * inv0;

        float m1 = fmaxf(lB0, lB1);
        m1 = fmaxf(m1, __shfl_xor(m1, 8, 64));
        m1 = fmaxf(m1, __shfl_xor(m1, 16, 64));
        m1 = fmaxf(m1, __shfl_xor(m1, 32, 64));
        float e10 = __expf(lB0 - m1), e11 = __expf(lB1 - m1);
        float s1 = e10 + e11;
        s1 += __shfl_xor(s1, 8, 64);
        s1 += __shfl_xor(s1, 16, 64);
        s1 += __shfl_xor(s1, 32, 64);
        float inv1 = 1.0f / s1;
        w21[s2n * 8 + s2s]       = e10 * inv1;
        w21[(s2n + 8) * 8 + s2s] = e11 * inv1;
    }
    __syncthreads();

    // ---- stage 5 (both points): out[c] = sum_n pv[n] * w[n][c&7] ----
    f32x2 ov0 = {0.0f, 0.0f}, ov1 = {0.0f, 0.0f};
#pragma unroll
    for (int n = 0; n < NSAMP; n += 2) {
        f32x2 p0 = {pv0[n], pv0[n + 1]};
        f32x2 w0 = {w20[n * 8 + s2s], w20[(n + 1) * 8 + s2s]};
        f32x2 p1 = {pv1[n], pv1[n + 1]};
        f32x2 w1 = {w21[n * 8 + s2s], w21[(n + 1) * 8 + s2s]};
        ov0 += p0 * w0;
        ov1 += p1 * w1;
    }
    float o0 = ov0.x + ov0.y;
    float o1 = ov1.x + ov1.y;
    if (isf32) {
        ((float*)OUT)[(size_t)i0 * 64 + c] = o0;
        ((float*)OUT)[(size_t)i1 * 64 + c] = o1;
    } else {
        ((__hip_bfloat16*)OUT)[(size_t)i0 * 64 + c] = __float2bfloat16(o0);
        ((__hip_bfloat16*)OUT)[(size_t)i1 * 64 + c] = __float2bfloat16(o1);
    }
}

// ---------------------------------------------------------------------------
extern "C" void kernel_launch(void* const* d_in, const int* in_sizes, int n_in,
                              void* d_out, int out_size, void* d_ws, size_t ws_size,
                              hipStream_t stream)
{
    const u16* p   = (const u16*)d_in[0];
    const u16* x   = (const u16*)d_in[1];
    const int* idx = (const int*)d_in[2];

    // workspace layout: cw 16KB + Q 25.6MB + KV 25.6MB ≈ 51.2 MB
    float* cw = (float*)d_ws;                   // 16 KB
    float* Q  = cw + CW_PAD;                    // N*64 f32 = 25.6 MB
    u32*   KV = (u32*)(Q + (size_t)N_PTS * 64); // N*64 u32 = 25.6 MB

    qkv_mfma_kernel<<<625, 256, 0, stream>>>(
        x,
        d_in[3],  d_in[4],  d_in[5],  d_in[6],  d_in[7],  d_in[8],
        d_in[9],  d_in[10], d_in[11], d_in[12], d_in[13], d_in[14],
        d_in[15], d_in[16], d_in[17], d_in[18], d_in[19], d_in[20],
        d_in[21], d_in[22], cw, Q, KV);                    // 625*10*16 = 100000
    attn_kernel<<<N_PTS / 8, 256, 0, stream>>>(p, idx, x, cw, Q, KV, d_out);
}